// Round 1
// 999.708 us; speedup vs baseline: 1.2908x; 1.2908x over previous
//
#include <hip/hip_runtime.h>
#include <cstdint>
#include <cstddef>

// Problem constants (from reference)
#define B_    2
#define S_    4096
#define H_    2048
#define D2_   1024
#define SCALE_ 0.125f

typedef __attribute__((ext_vector_type(8))) _Float16 half8;
typedef __attribute__((ext_vector_type(4))) float f32x4;

__device__ __forceinline__ ushort f2h(float f) {
    _Float16 h = (_Float16)f;
    return *(ushort*)&h;
}
__device__ __forceinline__ float h2f(ushort u) {
    return (float)(*(_Float16*)&u);
}

// async 16B global -> LDS (wave-uniform base + lane*16 semantics)
__device__ __forceinline__ void gld_lds16(const ushort* g, ushort* l) {
    __builtin_amdgcn_global_load_lds((const __attribute__((address_space(1))) void*)g,
                                     (__attribute__((address_space(3))) void*)l,
                                     16, 0, 0);
}

// ---------------- elementwise cast fp32 -> fp16, n4 = n/4 ----------------
__global__ __launch_bounds__(256) void cast_f16_kernel(const float* __restrict__ src,
                                                       ushort* __restrict__ dst, int n4) {
    int i = blockIdx.x * 256 + threadIdx.x;
    if (i < n4) {
        float4 v = ((const float4*)src)[i];
        ushort4 o;
        o.x = f2h(v.x); o.y = f2h(v.y); o.z = f2h(v.z); o.w = f2h(v.w);
        ((ushort4*)dst)[i] = o;
    }
}

__global__ __launch_bounds__(256) void cast4_f16_kernel(const float* __restrict__ w0,
                                                        const float* __restrict__ w1,
                                                        const float* __restrict__ w2,
                                                        const float* __restrict__ w3,
                                                        ushort* __restrict__ o0,
                                                        ushort* __restrict__ o1,
                                                        ushort* __restrict__ o2,
                                                        ushort* __restrict__ o3,
                                                        int n4) {
    int i = blockIdx.x * 256 + threadIdx.x;
    if (i >= n4) return;
    const float* s; ushort* d;
    switch (blockIdx.y) {
        case 0: s = w0; d = o0; break;
        case 1: s = w1; d = o1; break;
        case 2: s = w2; d = o2; break;
        default: s = w3; d = o3; break;
    }
    float4 v = ((const float4*)s)[i];
    ushort4 o;
    o.x = f2h(v.x); o.y = f2h(v.y); o.z = f2h(v.z); o.w = f2h(v.w);
    ((ushort4*)d)[i] = o;
}

// =================================================================================
// gemm256: C[M,N] = alpha * A[M,K] * B[N,K]^T, f16 in, f32/f16 out.
// 256x256 tile, BK=64, 512 threads = 8 waves (2M x 4N), per-wave 128x64 output.
// 8-phase pipelined schedule (T3+T4), counted vmcnt(4) per K-tile (never 0 in
// main loop), XOR-swizzled LDS (T2; linear gld_lds dest + inverse-swizzled
// global source, per rule #21), setprio around MFMA clusters (T5),
// bijective XCD blockIdx swizzle (T1). LDS = 128 KiB double buffer.
// =================================================================================
#define WAIT_VM(N) asm volatile("s_waitcnt vmcnt(" #N ")" ::: "memory")
#define WAIT_LGKM  asm volatile("s_waitcnt lgkmcnt(0)" ::: "memory")
#define BAR        __builtin_amdgcn_s_barrier()

template <int QM>
__device__ __forceinline__ void ld_a(const ushort* pA, int aRow0, int kx0, int kx1,
                                     half8 (&af)[4][2]) {
#pragma unroll
    for (int mi = 0; mi < 4; mi++) {
        af[mi][0] = *(const half8*)(pA + aRow0 + QM * 4096 + mi * 1024 + kx0);
        af[mi][1] = *(const half8*)(pA + aRow0 + QM * 4096 + mi * 1024 + kx1);
    }
}
template <int QN>
__device__ __forceinline__ void ld_b(const ushort* pB, int bRow0, int kx0, int kx1,
                                     half8 (&bf)[2][2][2]) {
#pragma unroll
    for (int ni = 0; ni < 2; ni++) {
        bf[QN][ni][0] = *(const half8*)(pB + bRow0 + QN * 2048 + ni * 1024 + kx0);
        bf[QN][ni][1] = *(const half8*)(pB + bRow0 + QN * 2048 + ni * 1024 + kx1);
    }
}
template <int QM, int QN>
__device__ __forceinline__ void mma(half8 (&af)[4][2], half8 (&bf)[2][2][2],
                                    f32x4 (&acc)[8][4]) {
    __builtin_amdgcn_s_setprio(1);
#pragma unroll
    for (int mi = 0; mi < 4; mi++)
#pragma unroll
        for (int ni = 0; ni < 2; ni++) {
            acc[QM * 4 + mi][QN * 2 + ni] = __builtin_amdgcn_mfma_f32_16x16x32_f16(
                af[mi][0], bf[QN][ni][0], acc[QM * 4 + mi][QN * 2 + ni], 0, 0, 0);
            acc[QM * 4 + mi][QN * 2 + ni] = __builtin_amdgcn_mfma_f32_16x16x32_f16(
                af[mi][1], bf[QN][ni][1], acc[QM * 4 + mi][QN * 2 + ni], 0, 0, 0);
        }
    __builtin_amdgcn_s_setprio(0);
}

// One K-tile = 4 phases. Phase q=(qm,qn): q0 reads A(qm=0)+B(qn=0) frags,
// q1 reads B(qn=1), q2 reads A(qm=1), q3 reads nothing. Staging: A halves of
// tile t+1 at q0/q1 (other buffer), B halves of tile t+2 at q2/q3 (slots whose
// last ds_read was in q0/q1 of this tile, one barrier earlier). vmcnt(4) at q3
// leaves exactly the two q2/q3 half-tiles (4 loads) outstanding => tile t+1
// fully landed before its q0 reads.
#define TILE(T_, STA_, STB_, VMC_)                                      \
    {                                                                   \
        const int bo_ = ((T_) & 1) << 14;                               \
        ld_a<0>(pAs + bo_, aRow0, kx0, kx1, af);                        \
        ld_b<0>(pBs + bo_, bRow0, kx0, kx1, bf);                        \
        if (STA_) stA((T_) + 1, 0);                                     \
        BAR; WAIT_LGKM;                                                 \
        mma<0, 0>(af, bf, acc);                                         \
        BAR;                                                            \
        ld_b<1>(pBs + bo_, bRow0, kx0, kx1, bf);                        \
        if (STA_) stA((T_) + 1, 1);                                     \
        BAR; WAIT_LGKM;                                                 \
        mma<0, 1>(af, bf, acc);                                         \
        BAR;                                                            \
        ld_a<1>(pAs + bo_, aRow0, kx0, kx1, af);                        \
        if (STB_) stB((T_) + 2, 0);                                     \
        BAR; WAIT_LGKM;                                                 \
        mma<1, 0>(af, bf, acc);                                         \
        BAR;                                                            \
        if (STB_) stB((T_) + 2, 1);                                     \
        VMC_;                                                           \
        BAR;                                                            \
        mma<1, 1>(af, bf, acc);                                         \
        BAR;                                                            \
    }

template <bool HALF_OUT>
__global__ __launch_bounds__(512, 2) void gemm256(const ushort* __restrict__ A,
                                                  const ushort* __restrict__ B,
                                                  void* __restrict__ Cv,
                                                  int M, int N, int K, float alpha,
                                                  size_t sA, size_t sB, size_t sC) {
    __shared__ __align__(16) ushort As[2][256][64];   // 64 KB
    __shared__ __align__(16) ushort Bs[2][256][64];   // 64 KB

    A += (size_t)blockIdx.z * sA;
    B += (size_t)blockIdx.z * sB;

    // T1: bijective XCD swizzle over the flattened 2D grid (nwg % 8 == 0 always here)
    const int nwg  = gridDim.x * gridDim.y;
    const int orig = blockIdx.y * gridDim.x + blockIdx.x;
    const int wg   = (orig & 7) * (nwg >> 3) + (orig >> 3);
    const int bm   = (wg / gridDim.x) * 256;
    const int bn   = (wg % gridDim.x) * 256;

    const int tid  = threadIdx.x;
    const int lane = tid & 63;
    const int wave = tid >> 6;     // 0..7
    const int wr   = wave >> 2;    // 0..1 -> 128-row half
    const int wc   = wave & 3;     // 0..3 -> 64-col slice
    const int col  = lane & 15;
    const int quad = lane >> 4;

    // ---- staging state: chunk c0 = tid (rows 0..63 of half), c1 = tid+512 (rows 64..127)
    // Inverse-swizzled global source: row r keeps its row, 16B-col = (c&7) ^ (r&7).
    const int srow = tid >> 3;                           // 0..63
    const int scol = ((tid & 7) ^ (srow & 7)) * 8;       // swizzled 16B column (elems)
    const ushort* gA = A + (size_t)(bm + srow) * K + scol;
    const ushort* gB = B + (size_t)(bn + srow) * K + scol;
    const size_t rs64  = (size_t)64 * K;
    const size_t rs128 = (size_t)128 * K;
    ushort* lA = &As[0][0][0] + tid * 8;                 // linear dest, byte tid*16
    ushort* lB = &Bs[0][0][0] + tid * 8;

    auto stA = [&](int t, int h) {
        const ushort* s = gA + (size_t)t * 64 + (h ? rs128 : (size_t)0);
        ushort* d = lA + ((t & 1) << 14) + (h << 13);
        gld_lds16(s, d);
        gld_lds16(s + rs64, d + 4096);
    };
    auto stB = [&](int t, int h) {
        const ushort* s = gB + (size_t)t * 64 + (h ? rs128 : (size_t)0);
        ushort* d = lB + ((t & 1) << 14) + (h << 13);
        gld_lds16(s, d);
        gld_lds16(s + rs64, d + 4096);
    };

    // ---- ds_read bases (swizzled): offset = row*64 + ((ksl*4+quad)^(col&7))*8 ushorts
    const int kx0   = ((quad ^ (col & 7)) * 8);
    const int kx1   = (((4 + quad) ^ (col & 7)) * 8);
    const int aRow0 = (wr * 128 + col) * 64;
    const int bRow0 = (wc * 64 + col) * 64;
    const ushort* pAs = &As[0][0][0];
    const ushort* pBs = &Bs[0][0][0];

    f32x4 acc[8][4];
#pragma unroll
    for (int i = 0; i < 8; i++)
#pragma unroll
        for (int j = 0; j < 4; j++) { f32x4 z = {0.f, 0.f, 0.f, 0.f}; acc[i][j] = z; }

    half8 af[4][2];
    half8 bf[2][2][2];

    const int T = K >> 6;   // K-tiles (K is 2048 or 4096 -> T = 32 or 64)

    // prologue: tile0 (B,A) + tile1 B; vmcnt(4) leaves tile1's B outstanding
    stB(0, 0); stB(0, 1); stA(0, 0); stA(0, 1); stB(1, 0); stB(1, 1);
    WAIT_VM(4);
    BAR;

    int t = 0;
    for (; t < T - 2; ++t) TILE(t, 1, 1, WAIT_VM(4));
    TILE(t, 1, 0, WAIT_VM(0));
    ++t;
    TILE(t, 0, 0, (void)0);

    // ---- epilogue: C/D layout col = lane&15, row = quad*4 + r [m89/m91]
    ushort* Ch = (ushort*)Cv + (size_t)blockIdx.z * sC;
    float*  Cf = (float*)Cv + (size_t)blockIdx.z * sC;
#pragma unroll
    for (int qm = 0; qm < 2; qm++)
#pragma unroll
        for (int mi = 0; mi < 4; mi++)
#pragma unroll
            for (int qn = 0; qn < 2; qn++)
#pragma unroll
                for (int ni = 0; ni < 2; ni++)
#pragma unroll
                    for (int r = 0; r < 4; r++) {
                        int grow = bm + wr * 128 + qm * 64 + mi * 16 + quad * 4 + r;
                        int gcol = bn + wc * 64 + qn * 32 + ni * 16 + col;
                        float val = alpha * acc[qm * 4 + mi][qn * 2 + ni][r];
                        if (HALF_OUT)
                            Ch[(size_t)grow * N + gcol] = f2h(val);
                        else
                            Cf[(size_t)grow * N + gcol] = val;
                    }
}

// ---------------- RoPE: f16 q,k in; interleaved f16 q_rot/k_rot + fp32 k_rot ------
__global__ __launch_bounds__(256) void rope_kernel(const ushort* __restrict__ qh,
                                                   const ushort* __restrict__ kh,
                                                   const float* __restrict__ cosT,
                                                   const float* __restrict__ sinT,
                                                   const int* __restrict__ pos,
                                                   ushort* __restrict__ qr,
                                                   ushort* __restrict__ kr,
                                                   float* __restrict__ krf32) {
    int idx = blockIdx.x * 256 + threadIdx.x;       // B*S*(D2/4) total
    int row = idx >> 8;                             // D2_/4 == 256
    int jj  = (idx & 255) * 4;
    int p = pos[row & (S_ - 1)];
    const ushort* q = qh + (size_t)row * H_ + jj;
    const ushort* k = kh + (size_t)row * H_ + jj;
    const float* cr = cosT + (size_t)p * D2_ + jj;
    const float* sr = sinT + (size_t)p * D2_ + jj;
    float4 c = *(const float4*)cr;
    float4 sn = *(const float4*)sr;
    ushort4 qr4 = *(const ushort4*)q;
    ushort4 qi4 = *(const ushort4*)(q + D2_);
    ushort4 kr4 = *(const ushort4*)k;
    ushort4 ki4 = *(const ushort4*)(k + D2_);

    float qrv[4] = {h2f(qr4.x), h2f(qr4.y), h2f(qr4.z), h2f(qr4.w)};
    float qiv[4] = {h2f(qi4.x), h2f(qi4.y), h2f(qi4.z), h2f(qi4.w)};
    float krv[4] = {h2f(kr4.x), h2f(kr4.y), h2f(kr4.z), h2f(kr4.w)};
    float kiv[4] = {h2f(ki4.x), h2f(ki4.y), h2f(ki4.z), h2f(ki4.w)};
    float cv[4] = {c.x, c.y, c.z, c.w};
    float sv[4] = {sn.x, sn.y, sn.z, sn.w};

    ushort qo[8], ko[8];
    float kf[8];
#pragma unroll
    for (int t = 0; t < 4; t++) {
        float o0 = qrv[t] * cv[t] - qiv[t] * sv[t];
        float o1 = qrv[t] * sv[t] + qiv[t] * cv[t];
        qo[2 * t] = f2h(o0); qo[2 * t + 1] = f2h(o1);
        float p0 = krv[t] * cv[t] - kiv[t] * sv[t];
        float p1 = krv[t] * sv[t] + kiv[t] * cv[t];
        ko[2 * t] = f2h(p0); ko[2 * t + 1] = f2h(p1);
        kf[2 * t] = p0; kf[2 * t + 1] = p1;
    }
    ushort* qro = qr + (size_t)row * H_ + 2 * jj;
    ushort* kro = kr + (size_t)row * H_ + 2 * jj;
    float* krf  = krf32 + (size_t)row * H_ + 2 * jj;
    *(ushort4*)(qro)     = *(ushort4*)(qo);
    *(ushort4*)(qro + 4) = *(ushort4*)(qo + 4);
    *(ushort4*)(kro)     = *(ushort4*)(ko);
    *(ushort4*)(kro + 4) = *(ushort4*)(ko + 4);
    *(float4*)(krf)      = *(float4*)(kf);
    *(float4*)(krf + 4)  = *(float4*)(kf + 4);
}

// ---------------- transpose+cast: v[b][s][h] fp32 -> vt[b][h][s] f16 ------------
__global__ __launch_bounds__(256) void transpose_cast_kernel(const float* __restrict__ v,
                                                             ushort* __restrict__ vt) {
    __shared__ float tile[32][33];
    int b  = blockIdx.z;
    int s0 = blockIdx.y * 32, h0 = blockIdx.x * 32;
    const float* vb = v + (size_t)b * S_ * H_;
    ushort* vtb = vt + (size_t)b * H_ * S_;
    int tx = threadIdx.x & 31, ty = threadIdx.x >> 5;
#pragma unroll
    for (int i = 0; i < 32; i += 8)
        tile[ty + i][tx] = vb[(size_t)(s0 + ty + i) * H_ + h0 + tx];
    __syncthreads();
#pragma unroll
    for (int i = 0; i < 32; i += 8)
        vtb[(size_t)(h0 + ty + i) * S_ + s0 + tx] = f2h(tile[tx][ty + i]);
}

// ---------------- row softmax: fp32 scores (4096 wide) -> f16 probs -------------
__global__ __launch_bounds__(256) void softmax_kernel(const float* __restrict__ sc,
                                                      ushort* __restrict__ pr) {
    __shared__ float red[8];
    size_t row = blockIdx.x;
    const float4* r = (const float4*)(sc + row * (size_t)S_);
    int tid = threadIdx.x;
    float4 v[4];
    float m = -1e30f;
#pragma unroll
    for (int i = 0; i < 4; i++) {
        v[i] = r[tid + i * 256];
        m = fmaxf(m, fmaxf(fmaxf(v[i].x, v[i].y), fmaxf(v[i].z, v[i].w)));
    }
#pragma unroll
    for (int off = 32; off >= 1; off >>= 1) m = fmaxf(m, __shfl_xor(m, off));
    if ((tid & 63) == 0) red[tid >> 6] = m;
    __syncthreads();
    m = fmaxf(fmaxf(red[0], red[1]), fmaxf(red[2], red[3]));
    float s = 0.f;
#pragma unroll
    for (int i = 0; i < 4; i++) {
        v[i].x = __expf(v[i].x - m); v[i].y = __expf(v[i].y - m);
        v[i].z = __expf(v[i].z - m); v[i].w = __expf(v[i].w - m);
        s += v[i].x + v[i].y + v[i].z + v[i].w;
    }
#pragma unroll
    for (int off = 32; off >= 1; off >>= 1) s += __shfl_xor(s, off);
    if ((tid & 63) == 0) red[4 + (tid >> 6)] = s;
    __syncthreads();
    float inv = 1.0f / (red[4] + red[5] + red[6] + red[7]);
    ushort4* o = (ushort4*)(pr + row * (size_t)S_);
#pragma unroll
    for (int i = 0; i < 4; i++) {
        ushort4 u;
        u.x = f2h(v[i].x * inv); u.y = f2h(v[i].y * inv);
        u.z = f2h(v[i].z * inv); u.w = f2h(v[i].w * inv);
        o[tid + i * 256] = u;
    }
}

// =================================================================================
extern "C" void kernel_launch(void* const* d_in, const int* in_sizes, int n_in,
                              void* d_out, int out_size, void* d_ws, size_t ws_size,
                              hipStream_t stream) {
    const float* hs   = (const float*)d_in[0];
    const float* wq   = (const float*)d_in[1];
    const float* wk   = (const float*)d_in[2];
    const float* wv   = (const float*)d_in[3];
    const float* wo   = (const float*)d_in[4];
    const float* fcos = (const float*)d_in[5];
    const float* fsin = (const float*)d_in[6];
    const int*   pos  = (const int*)d_in[7];

    const size_t BSH = (size_t)B_ * S_ * H_;   // 16,777,216
    const size_t HH  = (size_t)H_ * H_;        //  4,194,304

    float* out      = (float*)d_out;           // [0] output (B,S,H)
    float* krot_out = out + BSH;               // [1] k_rot  (B,S,H)
    float* v_out    = krot_out + BSH;          // [2] v      (B,S,H)

    char* ws = (char*)d_ws;
    const size_t MB = 1ull << 20;
    ushort* Xb  = (ushort*)(ws + 0);
    ushort* Wqb = (ushort*)(ws + 32 * MB);
    ushort* Wkb = (ushort*)(ws + 40 * MB);
    ushort* Wvb = (ushort*)(ws + 48 * MB);
    ushort* Wob = (ushort*)(ws + 56 * MB);
    ushort* qh  = (ushort*)(ws + 64 * MB);
    ushort* kh  = (ushort*)(ws + 96 * MB);
    ushort* qrb = (ushort*)(ws + 128 * MB);
    ushort* krb = (ushort*)(ws + 160 * MB);
    ushort* vtb = (ushort*)(ws + 192 * MB);
    float*  sc  = (float*)(ws + 224 * MB);
    ushort* prb = (ushort*)(ws + 64 * MB);     // reuse qh+kh (dead after rope)
    ushort* cb  = (ushort*)(ws + 128 * MB);    // reuse qrb (dead after scores)

    // 1. casts to f16
    cast_f16_kernel<<<(int)(BSH / 4 / 256), 256, 0, stream>>>(hs, Xb, (int)(BSH / 4));
    cast4_f16_kernel<<<dim3((int)(HH / 4 / 256), 4), 256, 0, stream>>>(
        wq, wk, wv, wo, Wqb, Wkb, Wvb, Wob, (int)(HH / 4));

    // 2. Q/K/V projections (C = X * W^T); Q/K straight to f16, V to fp32 output
    dim3 gProj(H_ / 256, (B_ * S_) / 256, 1);  // (8, 32) = 256 blocks
    gemm256<true ><<<gProj, 512, 0, stream>>>(Xb, Wqb, qh,    B_ * S_, H_, H_, 1.0f, 0, 0, 0);
    gemm256<true ><<<gProj, 512, 0, stream>>>(Xb, Wkb, kh,    B_ * S_, H_, H_, 1.0f, 0, 0, 0);
    gemm256<false><<<gProj, 512, 0, stream>>>(Xb, Wvb, v_out, B_ * S_, H_, H_, 1.0f, 0, 0, 0);

    // 3. RoPE (f16 q_rot/k_rot for attention + fp32 k_rot output)
    rope_kernel<<<(B_ * S_ * (D2_ / 4)) / 256, 256, 0, stream>>>(
        qh, kh, fcos, fsin, pos, qrb, krb, krot_out);

    // 4. v^T in f16 for the PV GEMM
    transpose_cast_kernel<<<dim3(H_ / 32, S_ / 32, B_), 256, 0, stream>>>(v_out, vtb);

    // 5. scores = SCALE * q_rot k_rot^T, both batches in one launch (z)
    dim3 gSc(S_ / 256, S_ / 256, B_);          // (16, 16, 2)
    gemm256<false><<<gSc, 512, 0, stream>>>(qrb, krb, sc, S_, S_, H_, SCALE_,
                                            (size_t)S_ * H_, (size_t)S_ * H_,
                                            (size_t)S_ * S_);

    // 6. softmax rows -> f16 probs
    softmax_kernel<<<B_ * S_, 256, 0, stream>>>(sc, prb);

    // 7. ctx = probs @ v (as probs * (v^T)^T), f16 out, both batches via z
    dim3 gPV(H_ / 256, S_ / 256, B_);          // (8, 16, 2) = 256 blocks
    gemm256<true><<<gPV, 512, 0, stream>>>(prb, vtb, cb, S_, H_, S_, 1.0f,
                                           (size_t)S_ * S_, (size_t)H_ * S_,
                                           (size_t)S_ * H_);

    // 8. output projection
    gemm256<false><<<gProj, 512, 0, stream>>>(cb, Wob, out, B_ * S_, H_, H_, 1.0f, 0, 0, 0);
}

// Round 3
// 982.962 us; speedup vs baseline: 1.3128x; 1.0170x over previous
//
#include <hip/hip_runtime.h>
#include <cstdint>
#include <cstddef>

// Problem constants (from reference)
#define B_    2
#define S_    4096
#define H_    2048
#define D2_   1024
#define SCALE_ 0.125f

typedef __attribute__((ext_vector_type(8))) _Float16 half8;
typedef __attribute__((ext_vector_type(4))) float f32x4;

__device__ __forceinline__ ushort f2h(float f) {
    _Float16 h = (_Float16)f;
    return *(ushort*)&h;
}
__device__ __forceinline__ float h2f(ushort u) {
    return (float)(*(_Float16*)&u);
}

// async 16B global -> LDS (wave-uniform base + lane*16 semantics)
__device__ __forceinline__ void gld_lds16(const ushort* g, ushort* l) {
    __builtin_amdgcn_global_load_lds((const __attribute__((address_space(1))) void*)g,
                                     (__attribute__((address_space(3))) void*)l,
                                     16, 0, 0);
}

// ---------------- elementwise cast fp32 -> fp16, n4 = n/4 ----------------
__global__ __launch_bounds__(256) void cast_f16_kernel(const float* __restrict__ src,
                                                       ushort* __restrict__ dst, int n4) {
    int i = blockIdx.x * 256 + threadIdx.x;
    if (i < n4) {
        float4 v = ((const float4*)src)[i];
        ushort4 o;
        o.x = f2h(v.x); o.y = f2h(v.y); o.z = f2h(v.z); o.w = f2h(v.w);
        ((ushort4*)dst)[i] = o;
    }
}

__global__ __launch_bounds__(256) void cast4_f16_kernel(const float* __restrict__ w0,
                                                        const float* __restrict__ w1,
                                                        const float* __restrict__ w2,
                                                        const float* __restrict__ w3,
                                                        ushort* __restrict__ o0,
                                                        ushort* __restrict__ o1,
                                                        ushort* __restrict__ o2,
                                                        ushort* __restrict__ o3,
                                                        int n4) {
    int i = blockIdx.x * 256 + threadIdx.x;
    if (i >= n4) return;
    const float* s; ushort* d;
    switch (blockIdx.y) {
        case 0: s = w0; d = o0; break;
        case 1: s = w1; d = o1; break;
        case 2: s = w2; d = o2; break;
        default: s = w3; d = o3; break;
    }
    float4 v = ((const float4*)s)[i];
    ushort4 o;
    o.x = f2h(v.x); o.y = f2h(v.y); o.z = f2h(v.z); o.w = f2h(v.w);
    ((ushort4*)d)[i] = o;
}

// =================================================================================
// gemm256: C[M,N] = alpha * A[M,K] * B[N,K]^T, f16 in, f32/f16 out.
// 256x256 tile, BK=64, 512 threads = 8 waves (2M x 4N), per-wave 128x64 output.
// ONE barrier + ONE vmcnt(0) per K-tile, in the proven order:
//   stage(t+1) ... compute(t) ... vmcnt(0) -> s_barrier -> pre-read(t+1).
// The barrier after vmcnt makes OTHER waves' staging visible before the
// pre-read (round-2 bug: vmcnt is per-wave; pre-read without a barrier read
// slots whose staging loads from other waves hadn't landed -> NaN).
// The top-of-loop barrier is redundant: all reads of the buffer being staged
// completed before each wave's bottom barrier of the previous iteration.
// XOR-swizzled LDS (T2, linear gld_lds dest + inverse-swizzled global source),
// setprio around MFMA clusters (T5), bijective XCD swizzle (T1).
// LDS = 128 KiB double buffer => 1 block/CU regardless of VGPRs, so
// __launch_bounds__(512,1): full register budget, no spill.
// =================================================================================
#define WAIT_VM(N) asm volatile("s_waitcnt vmcnt(" #N ")" ::: "memory")
#define BAR        __builtin_amdgcn_s_barrier()

template <int QM>
__device__ __forceinline__ void ld_a(const ushort* pA, int aRow0, int kx0, int kx1,
                                     half8 (&af)[4][2]) {
#pragma unroll
    for (int mi = 0; mi < 4; mi++) {
        af[mi][0] = *(const half8*)(pA + aRow0 + QM * 4096 + mi * 1024 + kx0);
        af[mi][1] = *(const half8*)(pA + aRow0 + QM * 4096 + mi * 1024 + kx1);
    }
}
template <int QN>
__device__ __forceinline__ void ld_b(const ushort* pB, int bRow0, int kx0, int kx1,
                                     half8 (&bf)[2][2]) {
#pragma unroll
    for (int ni = 0; ni < 2; ni++) {
        bf[ni][0] = *(const half8*)(pB + bRow0 + QN * 2048 + ni * 1024 + kx0);
        bf[ni][1] = *(const half8*)(pB + bRow0 + QN * 2048 + ni * 1024 + kx1);
    }
}
template <int QM, int QN>
__device__ __forceinline__ void mma(const half8 (&af)[4][2], const half8 (&bf)[2][2],
                                    f32x4 (&acc)[8][4]) {
    __builtin_amdgcn_s_setprio(1);
#pragma unroll
    for (int mi = 0; mi < 4; mi++)
#pragma unroll
        for (int ni = 0; ni < 2; ni++) {
            f32x4 c = acc[QM * 4 + mi][QN * 2 + ni];
            c = __builtin_amdgcn_mfma_f32_16x16x32_f16(af[mi][0], bf[ni][0], c, 0, 0, 0);
            c = __builtin_amdgcn_mfma_f32_16x16x32_f16(af[mi][1], bf[ni][1], c, 0, 0, 0);
            acc[QM * 4 + mi][QN * 2 + ni] = c;
        }
    __builtin_amdgcn_s_setprio(0);
}

template <bool HALF_OUT>
__global__ __launch_bounds__(512, 1) void gemm256(const ushort* __restrict__ A,
                                                  const ushort* __restrict__ B,
                                                  void* __restrict__ Cv,
                                                  int M, int N, int K, float alpha,
                                                  size_t sA, size_t sB, size_t sC) {
    __shared__ __align__(16) ushort As[2][256][64];   // 64 KB
    __shared__ __align__(16) ushort Bs[2][256][64];   // 64 KB

    A += (size_t)blockIdx.z * sA;
    B += (size_t)blockIdx.z * sB;

    // T1: bijective XCD swizzle over the flattened 2D grid (nwg % 8 == 0 always here)
    const int nwg  = gridDim.x * gridDim.y;
    const int orig = blockIdx.y * gridDim.x + blockIdx.x;
    const int wg   = (orig & 7) * (nwg >> 3) + (orig >> 3);
    const int bm   = (wg / gridDim.x) * 256;
    const int bn   = (wg % gridDim.x) * 256;

    const int tid  = threadIdx.x;
    const int lane = tid & 63;
    const int wave = tid >> 6;     // 0..7
    const int wr   = wave >> 2;    // 0..1 -> 128-row half
    const int wc   = wave & 3;     // 0..3 -> 64-col slice
    const int col  = lane & 15;
    const int quad = lane >> 4;

    // ---- staging: chunk = tid (rows 0..63 of half) and tid+512 (rows 64..127).
    // Inverse-swizzled global source: row r keeps its row, 16B-col = (c&7) ^ (r&7).
    const int srow = tid >> 3;                           // 0..63
    const int scol = ((tid & 7) ^ (srow & 7)) * 8;       // swizzled 16B column (elems)
    const ushort* gA = A + (size_t)(bm + srow) * K + scol;
    const ushort* gB = B + (size_t)(bn + srow) * K + scol;
    const size_t rs64  = (size_t)64 * K;
    const size_t rs128 = (size_t)128 * K;
    ushort* lA = &As[0][0][0] + tid * 8;                 // linear dest, byte tid*16
    ushort* lB = &Bs[0][0][0] + tid * 8;

    auto stA = [&](int t, int h) {
        const ushort* s = gA + (size_t)t * 64 + (h ? rs128 : (size_t)0);
        ushort* d = lA + ((t & 1) << 14) + (h << 13);
        gld_lds16(s, d);
        gld_lds16(s + rs64, d + 4096);
    };
    auto stB = [&](int t, int h) {
        const ushort* s = gB + (size_t)t * 64 + (h ? rs128 : (size_t)0);
        ushort* d = lB + ((t & 1) << 14) + (h << 13);
        gld_lds16(s, d);
        gld_lds16(s + rs64, d + 4096);
    };

    // ---- ds_read bases (swizzled): offset = row*64 + ((ksl*4+quad)^(col&7))*8 ushorts
    const int kx0   = ((quad ^ (col & 7)) * 8);
    const int kx1   = (((4 + quad) ^ (col & 7)) * 8);
    const int aRow0 = (wr * 128 + col) * 64;
    const int bRow0 = (wc * 64 + col) * 64;
    const ushort* pAs = &As[0][0][0];
    const ushort* pBs = &Bs[0][0][0];

    f32x4 acc[8][4];
#pragma unroll
    for (int i = 0; i < 8; i++)
#pragma unroll
        for (int j = 0; j < 4; j++) { f32x4 z = {0.f, 0.f, 0.f, 0.f}; acc[i][j] = z; }

    half8 af0[4][2], af1[4][2], bf0[2][2], bf1[2][2];

    const int T = K >> 6;   // K-tiles (K = 2048 or 4096 -> T = 32 or 64)

    // prologue: stage tile 0 into buf0; vmcnt -> barrier (cross-wave staging
    // visibility) -> pre-read its first-quadrant fragments.
    stA(0, 0); stA(0, 1); stB(0, 0); stB(0, 1);
    WAIT_VM(0);
    BAR;
    ld_a<0>(pAs, aRow0, kx0, kx1, af0);
    ld_b<0>(pBs, bRow0, kx0, kx1, bf0);

    for (int t = 0; t < T; ++t) {
        const int bo = (t & 1) << 14;
        // Stage tile t+1 into buf[(t+1)&1]. Safe: every wave's reads of that
        // buffer (tile t-1 compute + pre-reads) completed before the barrier
        // at the bottom of iteration t-1.
        if (t + 1 < T) {
            stA(t + 1, 0); stA(t + 1, 1); stB(t + 1, 0); stB(t + 1, 1);
        }
        // tile-t compute; af0/bf0 were pre-read after the previous barrier
        ld_a<1>(pAs + bo, aRow0, kx0, kx1, af1);
        mma<0, 0>(af0, bf0, acc);
        mma<1, 0>(af1, bf0, acc);
        ld_b<1>(pBs + bo, bRow0, kx0, kx1, bf1);
        mma<0, 1>(af0, bf1, acc);
        mma<1, 1>(af1, bf1, acc);
        if (t + 1 < T) {
            WAIT_VM(0);   // own staging loads done (issued a full tile ago)
            BAR;          // -> all waves' staging visible
            const int bo2 = ((t + 1) & 1) << 14;
            ld_a<0>(pAs + bo2, aRow0, kx0, kx1, af0);   // pre-read for next tile
            ld_b<0>(pBs + bo2, bRow0, kx0, kx1, bf0);
        }
    }

    // ---- epilogue: C/D layout col = lane&15, row = quad*4 + r [m89/m91]
    ushort* Ch = (ushort*)Cv + (size_t)blockIdx.z * sC;
    float*  Cf = (float*)Cv + (size_t)blockIdx.z * sC;
#pragma unroll
    for (int qm = 0; qm < 2; qm++)
#pragma unroll
        for (int mi = 0; mi < 4; mi++)
#pragma unroll
            for (int qn = 0; qn < 2; qn++)
#pragma unroll
                for (int ni = 0; ni < 2; ni++)
#pragma unroll
                    for (int r = 0; r < 4; r++) {
                        int grow = bm + wr * 128 + qm * 64 + mi * 16 + quad * 4 + r;
                        int gcol = bn + wc * 64 + qn * 32 + ni * 16 + col;
                        float val = alpha * acc[qm * 4 + mi][qn * 2 + ni][r];
                        if (HALF_OUT)
                            Ch[(size_t)grow * N + gcol] = f2h(val);
                        else
                            Cf[(size_t)grow * N + gcol] = val;
                    }
}

// ---------------- RoPE: f16 q,k in; interleaved f16 q_rot/k_rot + fp32 k_rot ------
__global__ __launch_bounds__(256) void rope_kernel(const ushort* __restrict__ qh,
                                                   const ushort* __restrict__ kh,
                                                   const float* __restrict__ cosT,
                                                   const float* __restrict__ sinT,
                                                   const int* __restrict__ pos,
                                                   ushort* __restrict__ qr,
                                                   ushort* __restrict__ kr,
                                                   float* __restrict__ krf32) {
    int idx = blockIdx.x * 256 + threadIdx.x;       // B*S*(D2/4) total
    int row = idx >> 8;                             // D2_/4 == 256
    int jj  = (idx & 255) * 4;
    int p = pos[row & (S_ - 1)];
    const ushort* q = qh + (size_t)row * H_ + jj;
    const ushort* k = kh + (size_t)row * H_ + jj;
    const float* cr = cosT + (size_t)p * D2_ + jj;
    const float* sr = sinT + (size_t)p * D2_ + jj;
    float4 c = *(const float4*)cr;
    float4 sn = *(const float4*)sr;
    ushort4 qr4 = *(const ushort4*)q;
    ushort4 qi4 = *(const ushort4*)(q + D2_);
    ushort4 kr4 = *(const ushort4*)k;
    ushort4 ki4 = *(const ushort4*)(k + D2_);

    float qrv[4] = {h2f(qr4.x), h2f(qr4.y), h2f(qr4.z), h2f(qr4.w)};
    float qiv[4] = {h2f(qi4.x), h2f(qi4.y), h2f(qi4.z), h2f(qi4.w)};
    float krv[4] = {h2f(kr4.x), h2f(kr4.y), h2f(kr4.z), h2f(kr4.w)};
    float kiv[4] = {h2f(ki4.x), h2f(ki4.y), h2f(ki4.z), h2f(ki4.w)};
    float cv[4] = {c.x, c.y, c.z, c.w};
    float sv[4] = {sn.x, sn.y, sn.z, sn.w};

    ushort qo[8], ko[8];
    float kf[8];
#pragma unroll
    for (int t = 0; t < 4; t++) {
        float o0 = qrv[t] * cv[t] - qiv[t] * sv[t];
        float o1 = qrv[t] * sv[t] + qiv[t] * cv[t];
        qo[2 * t] = f2h(o0); qo[2 * t + 1] = f2h(o1);
        float p0 = krv[t] * cv[t] - kiv[t] * sv[t];
        float p1 = krv[t] * sv[t] + kiv[t] * cv[t];
        ko[2 * t] = f2h(p0); ko[2 * t + 1] = f2h(p1);
        kf[2 * t] = p0; kf[2 * t + 1] = p1;
    }
    ushort* qro = qr + (size_t)row * H_ + 2 * jj;
    ushort* kro = kr + (size_t)row * H_ + 2 * jj;
    float* krf  = krf32 + (size_t)row * H_ + 2 * jj;
    *(ushort4*)(qro)     = *(ushort4*)(qo);
    *(ushort4*)(qro + 4) = *(ushort4*)(qo + 4);
    *(ushort4*)(kro)     = *(ushort4*)(ko);
    *(ushort4*)(kro + 4) = *(ushort4*)(ko + 4);
    *(float4*)(krf)      = *(float4*)(kf);
    *(float4*)(krf + 4)  = *(float4*)(kf + 4);
}

// ---------------- transpose+cast: v[b][s][h] fp32 -> vt[b][h][s] f16 ------------
__global__ __launch_bounds__(256) void transpose_cast_kernel(const float* __restrict__ v,
                                                             ushort* __restrict__ vt) {
    __shared__ float tile[32][33];
    int b  = blockIdx.z;
    int s0 = blockIdx.y * 32, h0 = blockIdx.x * 32;
    const float* vb = v + (size_t)b * S_ * H_;
    ushort* vtb = vt + (size_t)b * H_ * S_;
    int tx = threadIdx.x & 31, ty = threadIdx.x >> 5;
#pragma unroll
    for (int i = 0; i < 32; i += 8)
        tile[ty + i][tx] = vb[(size_t)(s0 + ty + i) * H_ + h0 + tx];
    __syncthreads();
#pragma unroll
    for (int i = 0; i < 32; i += 8)
        vtb[(size_t)(h0 + ty + i) * S_ + s0 + tx] = f2h(tile[tx][ty + i]);
}

// ---------------- row softmax: fp32 scores (4096 wide) -> f16 probs -------------
__global__ __launch_bounds__(256) void softmax_kernel(const float* __restrict__ sc,
                                                      ushort* __restrict__ pr) {
    __shared__ float red[8];
    size_t row = blockIdx.x;
    const float4* r = (const float4*)(sc + row * (size_t)S_);
    int tid = threadIdx.x;
    float4 v[4];
    float m = -1e30f;
#pragma unroll
    for (int i = 0; i < 4; i++) {
        v[i] = r[tid + i * 256];
        m = fmaxf(m, fmaxf(fmaxf(v[i].x, v[i].y), fmaxf(v[i].z, v[i].w)));
    }
#pragma unroll
    for (int off = 32; off >= 1; off >>= 1) m = fmaxf(m, __shfl_xor(m, off));
    if ((tid & 63) == 0) red[tid >> 6] = m;
    __syncthreads();
    m = fmaxf(fmaxf(red[0], red[1]), fmaxf(red[2], red[3]));
    float s = 0.f;
#pragma unroll
    for (int i = 0; i < 4; i++) {
        v[i].x = __expf(v[i].x - m); v[i].y = __expf(v[i].y - m);
        v[i].z = __expf(v[i].z - m); v[i].w = __expf(v[i].w - m);
        s += v[i].x + v[i].y + v[i].z + v[i].w;
    }
#pragma unroll
    for (int off = 32; off >= 1; off >>= 1) s += __shfl_xor(s, off);
    if ((tid & 63) == 0) red[4 + (tid >> 6)] = s;
    __syncthreads();
    float inv = 1.0f / (red[4] + red[5] + red[6] + red[7]);
    ushort4* o = (ushort4*)(pr + row * (size_t)S_);
#pragma unroll
    for (int i = 0; i < 4; i++) {
        ushort4 u;
        u.x = f2h(v[i].x * inv); u.y = f2h(v[i].y * inv);
        u.z = f2h(v[i].z * inv); u.w = f2h(v[i].w * inv);
        o[tid + i * 256] = u;
    }
}

// =================================================================================
extern "C" void kernel_launch(void* const* d_in, const int* in_sizes, int n_in,
                              void* d_out, int out_size, void* d_ws, size_t ws_size,
                              hipStream_t stream) {
    const float* hs   = (const float*)d_in[0];
    const float* wq   = (const float*)d_in[1];
    const float* wk   = (const float*)d_in[2];
    const float* wv   = (const float*)d_in[3];
    const float* wo   = (const float*)d_in[4];
    const float* fcos = (const float*)d_in[5];
    const float* fsin = (const float*)d_in[6];
    const int*   pos  = (const int*)d_in[7];

    const size_t BSH = (size_t)B_ * S_ * H_;   // 16,777,216
    const size_t HH  = (size_t)H_ * H_;        //  4,194,304

    float* out      = (float*)d_out;           // [0] output (B,S,H)
    float* krot_out = out + BSH;               // [1] k_rot  (B,S,H)
    float* v_out    = krot_out + BSH;          // [2] v      (B,S,H)

    char* ws = (char*)d_ws;
    const size_t MB = 1ull << 20;
    ushort* Xb  = (ushort*)(ws + 0);
    ushort* Wqb = (ushort*)(ws + 32 * MB);
    ushort* Wkb = (ushort*)(ws + 40 * MB);
    ushort* Wvb = (ushort*)(ws + 48 * MB);
    ushort* Wob = (ushort*)(ws + 56 * MB);
    ushort* qh  = (ushort*)(ws + 64 * MB);
    ushort* kh  = (ushort*)(ws + 96 * MB);
    ushort* qrb = (ushort*)(ws + 128 * MB);
    ushort* krb = (ushort*)(ws + 160 * MB);
    ushort* vtb = (ushort*)(ws + 192 * MB);
    float*  sc  = (float*)(ws + 224 * MB);
    ushort* prb = (ushort*)(ws + 64 * MB);     // reuse qh+kh (dead after rope)
    ushort* cb  = (ushort*)(ws + 128 * MB);    // reuse qrb (dead after scores)

    // 1. casts to f16
    cast_f16_kernel<<<(int)(BSH / 4 / 256), 256, 0, stream>>>(hs, Xb, (int)(BSH / 4));
    cast4_f16_kernel<<<dim3((int)(HH / 4 / 256), 4), 256, 0, stream>>>(
        wq, wk, wv, wo, Wqb, Wkb, Wvb, Wob, (int)(HH / 4));

    // 2. Q/K/V projections (C = X * W^T); Q/K straight to f16, V to fp32 output
    dim3 gProj(H_ / 256, (B_ * S_) / 256, 1);  // (8, 32) = 256 blocks
    gemm256<true ><<<gProj, 512, 0, stream>>>(Xb, Wqb, qh,    B_ * S_, H_, H_, 1.0f, 0, 0, 0);
    gemm256<true ><<<gProj, 512, 0, stream>>>(Xb, Wkb, kh,    B_ * S_, H_, H_, 1.0f, 0, 0, 0);
    gemm256<false><<<gProj, 512, 0, stream>>>(Xb, Wvb, v_out, B_ * S_, H_, H_, 1.0f, 0, 0, 0);

    // 3. RoPE (f16 q_rot/k_rot for attention + fp32 k_rot output)
    rope_kernel<<<(B_ * S_ * (D2_ / 4)) / 256, 256, 0, stream>>>(
        qh, kh, fcos, fsin, pos, qrb, krb, krot_out);

    // 4. v^T in f16 for the PV GEMM
    transpose_cast_kernel<<<dim3(H_ / 32, S_ / 32, B_), 256, 0, stream>>>(v_out, vtb);

    // 5. scores = SCALE * q_rot k_rot^T, both batches in one launch (z)
    dim3 gSc(S_ / 256, S_ / 256, B_);          // (16, 16, 2)
    gemm256<false><<<gSc, 512, 0, stream>>>(qrb, krb, sc, S_, S_, H_, SCALE_,
                                            (size_t)S_ * H_, (size_t)S_ * H_,
                                            (size_t)S_ * S_);

    // 6. softmax rows -> f16 probs
    softmax_kernel<<<B_ * S_, 256, 0, stream>>>(sc, prb);

    // 7. ctx = probs @ v (as probs * (v^T)^T), f16 out, both batches via z
    dim3 gPV(H_ / 256, S_ / 256, B_);          // (8, 16, 2) = 256 blocks
    gemm256<true><<<gPV, 512, 0, stream>>>(prb, vtb, cb, S_, H_, S_, 1.0f,
                                           (size_t)S_ * S_, (size_t)H_ * S_,
                                           (size_t)S_ * H_);

    // 8. output projection
    gemm256<false><<<gProj, 512, 0, stream>>>(cb, Wob, out, B_ * S_, H_, H_, 1.0f, 0, 0, 0);
}

// Round 4
// 855.943 us; speedup vs baseline: 1.5076x; 1.1484x over previous
//
#include <hip/hip_runtime.h>
#include <cstdint>
#include <cstddef>

// Problem constants (from reference)
#define B_    2
#define S_    4096
#define H_    2048
#define D2_   1024
#define SCALE_ 0.125f

typedef __attribute__((ext_vector_type(8))) _Float16 half8;
typedef __attribute__((ext_vector_type(4))) float f32x4;

__device__ __forceinline__ ushort f2h(float f) {
    _Float16 h = (_Float16)f;
    return *(ushort*)&h;
}
__device__ __forceinline__ float h2f(ushort u) {
    return (float)(*(_Float16*)&u);
}

// async 16B global -> LDS (wave-uniform base + lane*16 semantics)
__device__ __forceinline__ void gld_lds16(const ushort* g, ushort* l) {
    __builtin_amdgcn_global_load_lds((const __attribute__((address_space(1))) void*)g,
                                     (__attribute__((address_space(3))) void*)l,
                                     16, 0, 0);
}

// ---------------- elementwise cast fp32 -> fp16, n4 = n/4 ----------------
__global__ __launch_bounds__(256) void cast_f16_kernel(const float* __restrict__ src,
                                                       ushort* __restrict__ dst, int n4) {
    int i = blockIdx.x * 256 + threadIdx.x;
    if (i < n4) {
        float4 v = ((const float4*)src)[i];
        ushort4 o;
        o.x = f2h(v.x); o.y = f2h(v.y); o.z = f2h(v.z); o.w = f2h(v.w);
        ((ushort4*)dst)[i] = o;
    }
}

__global__ __launch_bounds__(256) void cast4_f16_kernel(const float* __restrict__ w0,
                                                        const float* __restrict__ w1,
                                                        const float* __restrict__ w2,
                                                        const float* __restrict__ w3,
                                                        ushort* __restrict__ o0,
                                                        ushort* __restrict__ o1,
                                                        ushort* __restrict__ o2,
                                                        ushort* __restrict__ o3,
                                                        int n4) {
    int i = blockIdx.x * 256 + threadIdx.x;
    if (i >= n4) return;
    const float* s; ushort* d;
    switch (blockIdx.y) {
        case 0: s = w0; d = o0; break;
        case 1: s = w1; d = o1; break;
        case 2: s = w2; d = o2; break;
        default: s = w3; d = o3; break;
    }
    float4 v = ((const float4*)s)[i];
    ushort4 o;
    o.x = f2h(v.x); o.y = f2h(v.y); o.z = f2h(v.z); o.w = f2h(v.w);
    ((ushort4*)d)[i] = o;
}

// =================================================================================
// gemm256: C[M,N] = alpha * A[M,K] * B[N,K]^T, f16 in, f32/f16 out.
// 256x256 tile, BK=64, 512 threads = 8 waves (2M x 4N), per-wave 128x64 output.
// Two barriers per K-tile split it into regions X and Y. Every LDS read is
// issued one region BEFORE its first consuming MFMA (no intra-region
// read->MFMA dependency), every MFMA cluster in a region is register-only wrt
// that region's reads -> LDS pipe and MFMA pipe overlap freely. Staging runs
// one tile ahead; both barrier waits are counted vmcnt(4) in steady state
// (never 0 -- T4):
//   X(t): vm(4)[A(t) landed] BAR | read af0(t) | stage A(t+1) | mma q10(t-1)
//   Y(t): vm(4)[B(t) landed] BAR | mma q11(t-1) | read bf0,bf1(t) |
//         stage B(t+1) | read af1(t) | mma q00(t) q01(t)
// Overwrite safety: A(t+1) overwrites A(t-1), last read in Y(t-1), fenced by
// bar1(t); B(t+1) overwrites B(t-1), last read in Y(t-1), two barriers back.
// XOR-swizzled LDS (T2), setprio on MFMA clusters (T5), XCD swizzle (T1).
// =================================================================================
#define WAIT_VM(N) asm volatile("s_waitcnt vmcnt(" #N ")" ::: "memory")
#define BAR        asm volatile("s_barrier" ::: "memory")

template <int QM>
__device__ __forceinline__ void ld_a(const ushort* pA, int aRow0, int kx0, int kx1,
                                     half8 (&af)[4][2]) {
#pragma unroll
    for (int mi = 0; mi < 4; mi++) {
        af[mi][0] = *(const half8*)(pA + aRow0 + QM * 4096 + mi * 1024 + kx0);
        af[mi][1] = *(const half8*)(pA + aRow0 + QM * 4096 + mi * 1024 + kx1);
    }
}
template <int QN>
__device__ __forceinline__ void ld_b(const ushort* pB, int bRow0, int kx0, int kx1,
                                     half8 (&bf)[2][2]) {
#pragma unroll
    for (int ni = 0; ni < 2; ni++) {
        bf[ni][0] = *(const half8*)(pB + bRow0 + QN * 2048 + ni * 1024 + kx0);
        bf[ni][1] = *(const half8*)(pB + bRow0 + QN * 2048 + ni * 1024 + kx1);
    }
}
template <int QM, int QN>
__device__ __forceinline__ void mma(const half8 (&af)[4][2], const half8 (&bf)[2][2],
                                    f32x4 (&acc)[8][4]) {
    __builtin_amdgcn_s_setprio(1);
#pragma unroll
    for (int mi = 0; mi < 4; mi++)
#pragma unroll
        for (int ni = 0; ni < 2; ni++) {
            f32x4 c = acc[QM * 4 + mi][QN * 2 + ni];
            c = __builtin_amdgcn_mfma_f32_16x16x32_f16(af[mi][0], bf[ni][0], c, 0, 0, 0);
            c = __builtin_amdgcn_mfma_f32_16x16x32_f16(af[mi][1], bf[ni][1], c, 0, 0, 0);
            acc[QM * 4 + mi][QN * 2 + ni] = c;
        }
    __builtin_amdgcn_s_setprio(0);
}

template <bool HALF_OUT>
__global__ __launch_bounds__(512, 1) void gemm256(const ushort* __restrict__ A,
                                                  const ushort* __restrict__ B,
                                                  void* __restrict__ Cv,
                                                  int M, int N, int K, float alpha,
                                                  size_t sA, size_t sB, size_t sC) {
    __shared__ __align__(16) ushort As[2][256][64];   // 64 KB
    __shared__ __align__(16) ushort Bs[2][256][64];   // 64 KB

    A += (size_t)blockIdx.z * sA;
    B += (size_t)blockIdx.z * sB;

    // T1: bijective XCD swizzle over the flattened 2D grid (nwg % 8 == 0 always here)
    const int nwg  = gridDim.x * gridDim.y;
    const int orig = blockIdx.y * gridDim.x + blockIdx.x;
    const int wg   = (orig & 7) * (nwg >> 3) + (orig >> 3);
    const int bm   = (wg / gridDim.x) * 256;
    const int bn   = (wg % gridDim.x) * 256;

    const int tid  = threadIdx.x;
    const int lane = tid & 63;
    const int wave = tid >> 6;     // 0..7
    const int wr   = wave >> 2;    // 0..1 -> 128-row half
    const int wc   = wave & 3;     // 0..3 -> 64-col slice
    const int col  = lane & 15;
    const int quad = lane >> 4;

    // ---- staging: chunk = tid (rows 0..63 of half) and tid+512 (rows 64..127).
    // Inverse-swizzled global source: row r keeps its row, 16B-col = (c&7) ^ (r&7).
    const int srow = tid >> 3;                           // 0..63
    const int scol = ((tid & 7) ^ (srow & 7)) * 8;       // swizzled 16B column (elems)
    const ushort* gA = A + (size_t)(bm + srow) * K + scol;
    const ushort* gB = B + (size_t)(bn + srow) * K + scol;
    const size_t rs64  = (size_t)64 * K;
    const size_t rs128 = (size_t)128 * K;
    ushort* lA = &As[0][0][0] + tid * 8;                 // linear dest, byte tid*16
    ushort* lB = &Bs[0][0][0] + tid * 8;

    auto stA = [&](int t, int h) {
        const ushort* s = gA + (size_t)t * 64 + (h ? rs128 : (size_t)0);
        ushort* d = lA + ((t & 1) << 14) + (h << 13);
        gld_lds16(s, d);
        gld_lds16(s + rs64, d + 4096);
    };
    auto stB = [&](int t, int h) {
        const ushort* s = gB + (size_t)t * 64 + (h ? rs128 : (size_t)0);
        ushort* d = lB + ((t & 1) << 14) + (h << 13);
        gld_lds16(s, d);
        gld_lds16(s + rs64, d + 4096);
    };

    // ---- ds_read bases (swizzled): offset = row*64 + ((ksl*4+quad)^(col&7))*8 ushorts
    const int kx0   = ((quad ^ (col & 7)) * 8);
    const int kx1   = (((4 + quad) ^ (col & 7)) * 8);
    const int aRow0 = (wr * 128 + col) * 64;
    const int bRow0 = (wc * 64 + col) * 64;
    const ushort* pAs = &As[0][0][0];
    const ushort* pBs = &Bs[0][0][0];

    f32x4 acc[8][4];
#pragma unroll
    for (int i = 0; i < 8; i++)
#pragma unroll
        for (int j = 0; j < 4; j++) { f32x4 z = {0.f, 0.f, 0.f, 0.f}; acc[i][j] = z; }

    half8 af0[4][2], af1[4][2], bf0[2][2], bf1[2][2];

    const int T = K >> 6;   // K-tiles (K = 2048 or 4096 -> T = 32 or 64)

    // prologue: issue tile-0 staging (A first, then B -- wait order relies on this)
    stA(0, 0); stA(0, 1); stB(0, 0); stB(0, 1);

    for (int t = 0; t < T; ++t) {
        const int bo = (t & 1) << 14;

        // ---- Region X(t) ----
        WAIT_VM(4);   // outstanding {A(t):4, B(t):4} -> waits A(t) landed
        BAR;          // cross-wave visibility of A(t); fences A(t+1) overwrite
        ld_a<0>(pAs + bo, aRow0, kx0, kx1, af0);     // 8 reads, used in Y(t)
        if (t + 1 < T) { stA(t + 1, 0); stA(t + 1, 1); }
        if (t > 0) mma<1, 0>(af1, bf0, acc);         // q10(t-1), register-only

        // ---- Region Y(t) ----
        if (t + 1 < T) { WAIT_VM(4); }               // {B(t):4, A(t+1):4} -> B(t) landed
        else           { WAIT_VM(0); }               // last tile: only B(t) outstanding
        BAR;          // visibility of B(t); fences B(t+1) overwrite
        if (t > 0) mma<1, 1>(af1, bf1, acc);         // q11(t-1), register-only
        ld_b<0>(pBs + bo, bRow0, kx0, kx1, bf0);     // 4 reads
        ld_b<1>(pBs + bo, bRow0, kx0, kx1, bf1);     // 4 reads
        if (t + 1 < T) { stB(t + 1, 0); stB(t + 1, 1); }
        ld_a<1>(pAs + bo, aRow0, kx0, kx1, af1);     // 8 reads, q10/q11 next iter
        mma<0, 0>(af0, bf0, acc);                    // af0 from X(t), bf0 just above
        mma<0, 1>(af0, bf1, acc);
    }
    // drain last tile's second A-half quadrants
    mma<1, 0>(af1, bf0, acc);
    mma<1, 1>(af1, bf1, acc);

    // ---- epilogue: C/D layout col = lane&15, row = quad*4 + r [m89/m91]
    ushort* Ch = (ushort*)Cv + (size_t)blockIdx.z * sC;
    float*  Cf = (float*)Cv + (size_t)blockIdx.z * sC;
#pragma unroll
    for (int qm = 0; qm < 2; qm++)
#pragma unroll
        for (int mi = 0; mi < 4; mi++)
#pragma unroll
            for (int qn = 0; qn < 2; qn++)
#pragma unroll
                for (int ni = 0; ni < 2; ni++)
#pragma unroll
                    for (int r = 0; r < 4; r++) {
                        int grow = bm + wr * 128 + qm * 64 + mi * 16 + quad * 4 + r;
                        int gcol = bn + wc * 64 + qn * 32 + ni * 16 + col;
                        float val = alpha * acc[qm * 4 + mi][qn * 2 + ni][r];
                        if (HALF_OUT)
                            Ch[(size_t)grow * N + gcol] = f2h(val);
                        else
                            Cf[(size_t)grow * N + gcol] = val;
                    }
}

// ---------------- RoPE: f16 q,k in; interleaved f16 q_rot/k_rot + fp32 k_rot ------
__global__ __launch_bounds__(256) void rope_kernel(const ushort* __restrict__ qh,
                                                   const ushort* __restrict__ kh,
                                                   const float* __restrict__ cosT,
                                                   const float* __restrict__ sinT,
                                                   const int* __restrict__ pos,
                                                   ushort* __restrict__ qr,
                                                   ushort* __restrict__ kr,
                                                   float* __restrict__ krf32) {
    int idx = blockIdx.x * 256 + threadIdx.x;       // B*S*(D2/4) total
    int row = idx >> 8;                             // D2_/4 == 256
    int jj  = (idx & 255) * 4;
    int p = pos[row & (S_ - 1)];
    const ushort* q = qh + (size_t)row * H_ + jj;
    const ushort* k = kh + (size_t)row * H_ + jj;
    const float* cr = cosT + (size_t)p * D2_ + jj;
    const float* sr = sinT + (size_t)p * D2_ + jj;
    float4 c = *(const float4*)cr;
    float4 sn = *(const float4*)sr;
    ushort4 qr4 = *(const ushort4*)q;
    ushort4 qi4 = *(const ushort4*)(q + D2_);
    ushort4 kr4 = *(const ushort4*)k;
    ushort4 ki4 = *(const ushort4*)(k + D2_);

    float qrv[4] = {h2f(qr4.x), h2f(qr4.y), h2f(qr4.z), h2f(qr4.w)};
    float qiv[4] = {h2f(qi4.x), h2f(qi4.y), h2f(qi4.z), h2f(qi4.w)};
    float krv[4] = {h2f(kr4.x), h2f(kr4.y), h2f(kr4.z), h2f(kr4.w)};
    float kiv[4] = {h2f(ki4.x), h2f(ki4.y), h2f(ki4.z), h2f(ki4.w)};
    float cv[4] = {c.x, c.y, c.z, c.w};
    float sv[4] = {sn.x, sn.y, sn.z, sn.w};

    ushort qo[8], ko[8];
    float kf[8];
#pragma unroll
    for (int t = 0; t < 4; t++) {
        float o0 = qrv[t] * cv[t] - qiv[t] * sv[t];
        float o1 = qrv[t] * sv[t] + qiv[t] * cv[t];
        qo[2 * t] = f2h(o0); qo[2 * t + 1] = f2h(o1);
        float p0 = krv[t] * cv[t] - kiv[t] * sv[t];
        float p1 = krv[t] * sv[t] + kiv[t] * cv[t];
        ko[2 * t] = f2h(p0); ko[2 * t + 1] = f2h(p1);
        kf[2 * t] = p0; kf[2 * t + 1] = p1;
    }
    ushort* qro = qr + (size_t)row * H_ + 2 * jj;
    ushort* kro = kr + (size_t)row * H_ + 2 * jj;
    float* krf  = krf32 + (size_t)row * H_ + 2 * jj;
    *(ushort4*)(qro)     = *(ushort4*)(qo);
    *(ushort4*)(qro + 4) = *(ushort4*)(qo + 4);
    *(ushort4*)(kro)     = *(ushort4*)(ko);
    *(ushort4*)(kro + 4) = *(ushort4*)(ko + 4);
    *(float4*)(krf)      = *(float4*)(kf);
    *(float4*)(krf + 4)  = *(float4*)(kf + 4);
}

// ---------------- transpose+cast: v[b][s][h] fp32 -> vt[b][h][s] f16 ------------
__global__ __launch_bounds__(256) void transpose_cast_kernel(const float* __restrict__ v,
                                                             ushort* __restrict__ vt) {
    __shared__ float tile[32][33];
    int b  = blockIdx.z;
    int s0 = blockIdx.y * 32, h0 = blockIdx.x * 32;
    const float* vb = v + (size_t)b * S_ * H_;
    ushort* vtb = vt + (size_t)b * H_ * S_;
    int tx = threadIdx.x & 31, ty = threadIdx.x >> 5;
#pragma unroll
    for (int i = 0; i < 32; i += 8)
        tile[ty + i][tx] = vb[(size_t)(s0 + ty + i) * H_ + h0 + tx];
    __syncthreads();
#pragma unroll
    for (int i = 0; i < 32; i += 8)
        vtb[(size_t)(h0 + ty + i) * S_ + s0 + tx] = f2h(tile[tx][ty + i]);
}

// ---------------- row softmax: fp32 scores (4096 wide) -> f16 probs -------------
__global__ __launch_bounds__(256) void softmax_kernel(const float* __restrict__ sc,
                                                      ushort* __restrict__ pr) {
    __shared__ float red[8];
    size_t row = blockIdx.x;
    const float4* r = (const float4*)(sc + row * (size_t)S_);
    int tid = threadIdx.x;
    float4 v[4];
    float m = -1e30f;
#pragma unroll
    for (int i = 0; i < 4; i++) {
        v[i] = r[tid + i * 256];
        m = fmaxf(m, fmaxf(fmaxf(v[i].x, v[i].y), fmaxf(v[i].z, v[i].w)));
    }
#pragma unroll
    for (int off = 32; off >= 1; off >>= 1) m = fmaxf(m, __shfl_xor(m, off));
    if ((tid & 63) == 0) red[tid >> 6] = m;
    __syncthreads();
    m = fmaxf(fmaxf(red[0], red[1]), fmaxf(red[2], red[3]));
    float s = 0.f;
#pragma unroll
    for (int i = 0; i < 4; i++) {
        v[i].x = __expf(v[i].x - m); v[i].y = __expf(v[i].y - m);
        v[i].z = __expf(v[i].z - m); v[i].w = __expf(v[i].w - m);
        s += v[i].x + v[i].y + v[i].z + v[i].w;
    }
#pragma unroll
    for (int off = 32; off >= 1; off >>= 1) s += __shfl_xor(s, off);
    if ((tid & 63) == 0) red[4 + (tid >> 6)] = s;
    __syncthreads();
    float inv = 1.0f / (red[4] + red[5] + red[6] + red[7]);
    ushort4* o = (ushort4*)(pr + row * (size_t)S_);
#pragma unroll
    for (int i = 0; i < 4; i++) {
        ushort4 u;
        u.x = f2h(v[i].x * inv); u.y = f2h(v[i].y * inv);
        u.z = f2h(v[i].z * inv); u.w = f2h(v[i].w * inv);
        o[tid + i * 256] = u;
    }
}

// =================================================================================
extern "C" void kernel_launch(void* const* d_in, const int* in_sizes, int n_in,
                              void* d_out, int out_size, void* d_ws, size_t ws_size,
                              hipStream_t stream) {
    const float* hs   = (const float*)d_in[0];
    const float* wq   = (const float*)d_in[1];
    const float* wk   = (const float*)d_in[2];
    const float* wv   = (const float*)d_in[3];
    const float* wo   = (const float*)d_in[4];
    const float* fcos = (const float*)d_in[5];
    const float* fsin = (const float*)d_in[6];
    const int*   pos  = (const int*)d_in[7];

    const size_t BSH = (size_t)B_ * S_ * H_;   // 16,777,216
    const size_t HH  = (size_t)H_ * H_;        //  4,194,304

    float* out      = (float*)d_out;           // [0] output (B,S,H)
    float* krot_out = out + BSH;               // [1] k_rot  (B,S,H)
    float* v_out    = krot_out + BSH;          // [2] v      (B,S,H)

    char* ws = (char*)d_ws;
    const size_t MB = 1ull << 20;
    ushort* Xb  = (ushort*)(ws + 0);
    ushort* Wqb = (ushort*)(ws + 32 * MB);
    ushort* Wkb = (ushort*)(ws + 40 * MB);
    ushort* Wvb = (ushort*)(ws + 48 * MB);
    ushort* Wob = (ushort*)(ws + 56 * MB);
    ushort* qh  = (ushort*)(ws + 64 * MB);
    ushort* kh  = (ushort*)(ws + 96 * MB);
    ushort* qrb = (ushort*)(ws + 128 * MB);
    ushort* krb = (ushort*)(ws + 160 * MB);
    ushort* vtb = (ushort*)(ws + 192 * MB);
    float*  sc  = (float*)(ws + 224 * MB);
    ushort* prb = (ushort*)(ws + 64 * MB);     // reuse qh+kh (dead after rope)
    ushort* cb  = (ushort*)(ws + 128 * MB);    // reuse qrb (dead after scores)

    // 1. casts to f16
    cast_f16_kernel<<<(int)(BSH / 4 / 256), 256, 0, stream>>>(hs, Xb, (int)(BSH / 4));
    cast4_f16_kernel<<<dim3((int)(HH / 4 / 256), 4), 256, 0, stream>>>(
        wq, wk, wv, wo, Wqb, Wkb, Wvb, Wob, (int)(HH / 4));

    // 2. Q/K/V projections (C = X * W^T); Q/K straight to f16, V to fp32 output
    dim3 gProj(H_ / 256, (B_ * S_) / 256, 1);  // (8, 32) = 256 blocks
    gemm256<true ><<<gProj, 512, 0, stream>>>(Xb, Wqb, qh,    B_ * S_, H_, H_, 1.0f, 0, 0, 0);
    gemm256<true ><<<gProj, 512, 0, stream>>>(Xb, Wkb, kh,    B_ * S_, H_, H_, 1.0f, 0, 0, 0);
    gemm256<false><<<gProj, 512, 0, stream>>>(Xb, Wvb, v_out, B_ * S_, H_, H_, 1.0f, 0, 0, 0);

    // 3. RoPE (f16 q_rot/k_rot for attention + fp32 k_rot output)
    rope_kernel<<<(B_ * S_ * (D2_ / 4)) / 256, 256, 0, stream>>>(
        qh, kh, fcos, fsin, pos, qrb, krb, krot_out);

    // 4. v^T in f16 for the PV GEMM
    transpose_cast_kernel<<<dim3(H_ / 32, S_ / 32, B_), 256, 0, stream>>>(v_out, vtb);

    // 5. scores = SCALE * q_rot k_rot^T, both batches in one launch (z)
    dim3 gSc(S_ / 256, S_ / 256, B_);          // (16, 16, 2)
    gemm256<false><<<gSc, 512, 0, stream>>>(qrb, krb, sc, S_, S_, H_, SCALE_,
                                            (size_t)S_ * H_, (size_t)S_ * H_,
                                            (size_t)S_ * S_);

    // 6. softmax rows -> f16 probs
    softmax_kernel<<<B_ * S_, 256, 0, stream>>>(sc, prb);

    // 7. ctx = probs @ v (as probs * (v^T)^T), f16 out, both batches via z
    dim3 gPV(H_ / 256, S_ / 256, B_);          // (8, 16, 2) = 256 blocks
    gemm256<true><<<gPV, 512, 0, stream>>>(prb, vtb, cb, S_, H_, S_, 1.0f,
                                           (size_t)S_ * S_, (size_t)H_ * S_,
                                           (size_t)S_ * H_);

    // 8. output projection
    gemm256<false><<<gProj, 512, 0, stream>>>(cb, Wob, out, B_ * S_, H_, H_, 1.0f, 0, 0, 0);
}